// Round 9
// baseline (2204.438 us; speedup 1.0000x reference)
//
#include <hip/hip_runtime.h>
#include <hip/hip_bf16.h>

typedef __bf16 bf16_t;
typedef __bf16 bf16x8 __attribute__((ext_vector_type(8)));
typedef float  f32x4  __attribute__((ext_vector_type(4)));

constexpr int T_ = 2048, H_ = 2048, I_ = 5632, E_ = 8, S_ = T_ * 2;

// ---- workspace layout (bytes) ----  total ~88.2 MB
constexpr size_t OFF_HB    = 0;                                   // bf16 hidden  [T][H]
constexpr size_t OFF_HOUT  = OFF_HB    + (size_t)T_ * H_ * 2;     // bf16 h       [S][I]
constexpr size_t OFF_DPART = OFF_HOUT  + (size_t)S_ * I_ * 2;     // f32 downpart [S][H]
constexpr size_t OFF_TOS   = OFF_DPART + (size_t)S_ * H_ * 4;     // int token_of_slot[S]
constexpr size_t OFF_SOT   = OFF_TOS   + (size_t)S_ * 4;          // int slot_of_tk[T*2]
constexpr size_t OFF_TKI   = OFF_SOT   + (size_t)S_ * 4;          // int topk_idx[T*2]
constexpr size_t OFF_TKW   = OFF_TKI   + (size_t)S_ * 4;          // f32 topk_w[T*2]
constexpr size_t OFF_CNT   = OFF_TKW   + (size_t)S_ * 4;          // int counts[E]
constexpr size_t OFF_OFFS  = OFF_CNT   + 64;                      // int offs[E]
constexpr size_t OFF_CUR   = OFF_OFFS  + 64;                      // int cursor[E]

// async global->LDS, 16B per lane. LDS dest = wave-uniform base + lane*16 (HW).
__device__ __forceinline__ void gload16(const void* g, void* l) {
  __builtin_amdgcn_global_load_lds(
      (const __attribute__((address_space(1))) void*)g,
      (__attribute__((address_space(3))) void*)l, 16, 0, 0);
}

__device__ __forceinline__ bf16x8 cvt8(f32x4 a, f32x4 b) {
  bf16x8 r;
  r[0]=(bf16_t)a[0]; r[1]=(bf16_t)a[1]; r[2]=(bf16_t)a[2]; r[3]=(bf16_t)a[3];
  r[4]=(bf16_t)b[0]; r[5]=(bf16_t)b[1]; r[6]=(bf16_t)b[2]; r[7]=(bf16_t)b[3];
  return r;
}

// ================= router: logits, softmax, top-2, bf16 convert =================
__global__ __launch_bounds__(256)
void router_kernel(const float* __restrict__ hs, const float* __restrict__ gw,
                   int* __restrict__ tki, float* __restrict__ tkw,
                   int* __restrict__ counts, bf16_t* __restrict__ hb)
{
  const int t = blockIdx.x;
  const int tid = threadIdx.x;
  const int lane = tid & 63, wid = tid >> 6;
  const float* hrow = hs + (size_t)t * H_;
  const int c0 = tid * 8;
  float4 h0 = *(const float4*)(hrow + c0);
  float4 h1 = *(const float4*)(hrow + c0 + 4);
  bf16x8 hv;
  hv[0]=(bf16_t)h0.x; hv[1]=(bf16_t)h0.y; hv[2]=(bf16_t)h0.z; hv[3]=(bf16_t)h0.w;
  hv[4]=(bf16_t)h1.x; hv[5]=(bf16_t)h1.y; hv[6]=(bf16_t)h1.z; hv[7]=(bf16_t)h1.w;
  *(bf16x8*)(hb + (size_t)t * H_ + c0) = hv;

  float acc[E_];
  #pragma unroll
  for (int e = 0; e < E_; ++e) {
    const float* g = gw + (size_t)e * H_ + c0;
    float4 g0 = *(const float4*)(g);
    float4 g1 = *(const float4*)(g + 4);
    acc[e] = h0.x*g0.x + h0.y*g0.y + h0.z*g0.z + h0.w*g0.w
           + h1.x*g1.x + h1.y*g1.y + h1.z*g1.z + h1.w*g1.w;
  }
  #pragma unroll
  for (int e = 0; e < E_; ++e)
    #pragma unroll
    for (int o = 32; o > 0; o >>= 1)
      acc[e] += __shfl_down(acc[e], o);
  __shared__ float red[4][E_];
  if (lane == 0)
    #pragma unroll
    for (int e = 0; e < E_; ++e) red[wid][e] = acc[e];
  __syncthreads();
  if (tid == 0) {
    float l[E_];
    #pragma unroll
    for (int e = 0; e < E_; ++e) l[e] = red[0][e] + red[1][e] + red[2][e] + red[3][e];
    float m = l[0];
    #pragma unroll
    for (int e = 1; e < E_; ++e) m = fmaxf(m, l[e]);
    float p[E_]; float s = 0.f;
    #pragma unroll
    for (int e = 0; e < E_; ++e) { p[e] = __expf(l[e] - m); s += p[e]; }
    int i1 = 0;
    #pragma unroll
    for (int e = 1; e < E_; ++e) if (l[e] > l[i1]) i1 = e;
    int i2 = (i1 == 0) ? 1 : 0;
    #pragma unroll
    for (int e = 0; e < E_; ++e) if (e != i1 && l[e] > l[i2]) i2 = e;
    tki[2*t] = i1; tki[2*t+1] = i2;
    tkw[2*t] = p[i1] / s; tkw[2*t+1] = p[i2] / s;
    atomicAdd(&counts[i1], 1);
    atomicAdd(&counts[i2], 1);
  }
}

// ================= scan: expert offsets + slot lists =================
__global__ void scan_kernel(const int* __restrict__ counts, const int* __restrict__ tki,
                            int* __restrict__ offs, int* __restrict__ cursor,
                            int* __restrict__ tos, int* __restrict__ sot)
{
  if (threadIdx.x == 0) {
    int run = 0;
    for (int e = 0; e < E_; ++e) { offs[e] = run; cursor[e] = run; run += counts[e]; }
  }
  __syncthreads();
  for (int t = threadIdx.x; t < T_; t += blockDim.x) {
    #pragma unroll
    for (int k = 0; k < 2; ++k) {
      int e = tki[2*t + k];
      int s = atomicAdd(&cursor[e], 1);
      tos[s] = t;
      sot[2*t + k] = s;
    }
  }
}

// ================= GEMM1: gathered hidden x w1^T, dual (gate,up), fused silu*mul =================
// B DIRECT global->reg (wave-private fragments, no LDS round-trip), pipelined 1 iter ahead:
//   loadB(t+1); stageA(t+1); compute(t) [uses frags cvt'd last iter]; cvt; barrier.
// LDS holds only A (gather): [128 rows][4x16B chunks], chunk' = chunk ^ (R&3) (2-way = free).
// BM=128, per-wave 64 rows x (32 gate + 32 up) cols, BK=32, NK=64.
constexpr int G1_BUF = 8192;

__global__ __launch_bounds__(256, 3)
void gemm1_kernel(const bf16_t* __restrict__ hb, const float* __restrict__ w1,
                  const int* __restrict__ tos, const int* __restrict__ offs,
                  const int* __restrict__ counts, bf16_t* __restrict__ hout)
{
  // XCD-pinned raster: expert e on XCD (bid&7); m-tiles innermost -> same-(e,n) strip L2/L3 reuse.
  const int bid = blockIdx.x;
  const int e   = bid & 7;
  const int idx = bid >> 3;          // 16 m-tiles x 88 n-tiles
  const int mt  = idx & 15;
  const int nt  = idx >> 4;

  const int cnt = counts[e];
  const int m0 = mt * 128;
  if (m0 >= cnt) return;
  const int off = offs[e];
  const int n0 = nt * 64;

  const float* Wg = w1 + (size_t)e * (2 * (size_t)I_ * H_) + (size_t)n0 * H_;

  __shared__ char smem[2 * G1_BUF];   // 16KB total

  const int tid = threadIdx.x;
  const int lane = tid & 63, wid = tid >> 6;
  const int wm = wid >> 1, wn = wid & 1;
  const int l15 = lane & 15, l4 = lane >> 4;

  // --- A staging: 8 chunks of 1KB (16 rows x 64B); wave stages q = wid*2+{0,1}.
  // lane -> R = q*16+(lane>>2), phys chunk = lane&3, wanted = phys ^ (R&3).
  const bf16_t* agp[2]; int aoff[2];
  #pragma unroll
  for (int i = 0; i < 2; ++i) {
    int q = wid * 2 + i;
    int R = q * 16 + (lane >> 2);
    int wanted = (lane & 3) ^ ((lane >> 2) & 3);
    int slot = off + m0 + R, mx = off + cnt - 1;
    if (slot > mx) slot = mx;            // clamp pad rows (masked at store)
    agp[i]  = hb + (size_t)tos[slot] * H_ + wanted * 8;
    aoff[i] = q * 1024;
  }
  auto stageA = [&](int b, int t) {
    char* ab = smem + b * G1_BUF;
    #pragma unroll
    for (int i = 0; i < 2; ++i) gload16(agp[i] + t * 32, ab + aoff[i]);
  };

  // --- B direct pointers: per lane, rows of w1 (gate: n0+wn*32+ni*16+l15; up: +I_), k base l4*8.
  const float* bp00 = Wg + (size_t)(wn * 32 +  0 + l15) * H_ + l4 * 8;
  const float* bp01 = Wg + (size_t)(wn * 32 + 16 + l15) * H_ + l4 * 8;
  const float* bp10 = bp00 + (size_t)I_ * H_;
  const float* bp11 = bp01 + (size_t)I_ * H_;

  f32x4 br0, br1, br2, br3, br4, br5, br6, br7;
  auto loadB = [&](int k0) {
    br0 = *(const f32x4*)(bp00 + k0); br1 = *(const f32x4*)(bp00 + k0 + 4);
    br2 = *(const f32x4*)(bp01 + k0); br3 = *(const f32x4*)(bp01 + k0 + 4);
    br4 = *(const f32x4*)(bp10 + k0); br5 = *(const f32x4*)(bp10 + k0 + 4);
    br6 = *(const f32x4*)(bp11 + k0); br7 = *(const f32x4*)(bp11 + k0 + 4);
  };
  bf16x8 bgf0, bgf1, buf0, buf1;     // persistent frags (converted one iter ahead)
  auto cvtB = [&]() {
    bgf0 = cvt8(br0, br1); bgf1 = cvt8(br2, br3);
    buf0 = cvt8(br4, br5); buf1 = cvt8(br6, br7);
  };

  f32x4 accg[4][2], accu[4][2];
  #pragma unroll
  for (int mi = 0; mi < 4; ++mi)
    #pragma unroll
    for (int ni = 0; ni < 2; ++ni) {
      accg[mi][ni] = f32x4{0.f,0.f,0.f,0.f};
      accu[mi][ni] = f32x4{0.f,0.f,0.f,0.f};
    }

  const int achunk = (l4 ^ (l15 & 3)) * 16;   // read-side swizzled chunk byte
  auto compute = [&](int b) {
    const char* ab = smem + b * G1_BUF;
    bf16x8 af[4];
    #pragma unroll
    for (int mi = 0; mi < 4; ++mi) {
      int R = wm * 64 + mi * 16 + l15;
      af[mi] = *(const bf16x8*)(ab + R * 64 + achunk);
    }
    #pragma unroll
    for (int mi = 0; mi < 4; ++mi) {
      accg[mi][0] = __builtin_amdgcn_mfma_f32_16x16x32_bf16(af[mi], bgf0, accg[mi][0], 0, 0, 0);
      accg[mi][1] = __builtin_amdgcn_mfma_f32_16x16x32_bf16(af[mi], bgf1, accg[mi][1], 0, 0, 0);
      accu[mi][0] = __builtin_amdgcn_mfma_f32_16x16x32_bf16(af[mi], buf0, accu[mi][0], 0, 0, 0);
      accu[mi][1] = __builtin_amdgcn_mfma_f32_16x16x32_bf16(af[mi], buf1, accu[mi][1], 0, 0, 0);
    }
  };

  constexpr int NK = H_ / 32;   // 64
  loadB(0); stageA(0, 0);
  cvtB();                        // waits B(0); A(0) drains at barrier
  __syncthreads();
  int cur = 0;
  for (int t = 0; t < NK; ++t) {
    if (t + 1 < NK) { loadB((t + 1) * 32); stageA(cur ^ 1, t + 1); }
    compute(cur);                // uses bfrags(t) + LDS A(t)
    if (t + 1 < NK) cvtB();      // vm-wait lands AFTER compute
    __syncthreads();
    cur ^= 1;
  }

  // epilogue: silu(g)*u -> bf16 h[slot][i]   (C/D map: row=(lane>>4)*4+j, col=lane&15)
  #pragma unroll
  for (int mi = 0; mi < 4; ++mi)
    #pragma unroll
    for (int ni = 0; ni < 2; ++ni)
      #pragma unroll
      for (int j = 0; j < 4; ++j) {
        int rel = wm*64 + mi*16 + l4*4 + j;
        if (m0 + rel < cnt) {
          int col = n0 + wn*32 + ni*16 + l15;
          float g = accg[mi][ni][j];
          float u = accu[mi][ni][j];
          float hvv = (g / (1.0f + __expf(-g))) * u;
          hout[(size_t)(off + m0 + rel) * I_ + col] = (bf16_t)hvv;
        }
      }
}

// ================= GEMM2: h x w2^T -> per-slot partial (f32) =================
// Same B-direct structure. BM=128, BN=128 (per wave 64x64), BK=32, NK=176.
constexpr int G2_BUF = 8192;

__global__ __launch_bounds__(256, 3)
void gemm2_kernel(const bf16_t* __restrict__ hbuf, const float* __restrict__ w2,
                  const int* __restrict__ offs, const int* __restrict__ counts,
                  float* __restrict__ dpart)
{
  const int bid = blockIdx.x;
  const int e   = bid & 7;
  const int idx = bid >> 3;          // 16 m x 16 n
  const int mt  = idx & 15;
  const int nt  = idx >> 4;

  const int cnt = counts[e];
  const int m0 = mt * 128;
  if (m0 >= cnt) return;
  const int off = offs[e];
  const int n0 = nt * 128;
  const float* W = w2 + (size_t)e * ((size_t)H_ * I_) + (size_t)n0 * I_;

  __shared__ char smem[2 * G2_BUF];

  const int tid = threadIdx.x;
  const int lane = tid & 63, wid = tid >> 6;
  const int wm = wid >> 1, wn = wid & 1;
  const int l15 = lane & 15, l4 = lane >> 4;

  // A staging (rows are slots, contiguous; clamp tail)
  const bf16_t* agp[2]; int aoff[2];
  #pragma unroll
  for (int i = 0; i < 2; ++i) {
    int q = wid * 2 + i;
    int R = q * 16 + (lane >> 2);
    int wanted = (lane & 3) ^ ((lane >> 2) & 3);
    int slot = off + m0 + R, mx = off + cnt - 1;
    if (slot > mx) slot = mx;
    agp[i]  = hbuf + (size_t)slot * I_ + wanted * 8;
    aoff[i] = q * 1024;
  }
  auto stageA = [&](int b, int t) {
    char* ab = smem + b * G2_BUF;
    #pragma unroll
    for (int i = 0; i < 2; ++i) gload16(agp[i] + t * 32, ab + aoff[i]);
  };

  const float* bp0 = W + (size_t)(wn * 64 +  0 + l15) * I_ + l4 * 8;
  const float* bp1 = W + (size_t)(wn * 64 + 16 + l15) * I_ + l4 * 8;
  const float* bp2 = W + (size_t)(wn * 64 + 32 + l15) * I_ + l4 * 8;
  const float* bp3 = W + (size_t)(wn * 64 + 48 + l15) * I_ + l4 * 8;

  f32x4 br0, br1, br2, br3, br4, br5, br6, br7;
  auto loadB = [&](int k0) {
    br0 = *(const f32x4*)(bp0 + k0); br1 = *(const f32x4*)(bp0 + k0 + 4);
    br2 = *(const f32x4*)(bp1 + k0); br3 = *(const f32x4*)(bp1 + k0 + 4);
    br4 = *(const f32x4*)(bp2 + k0); br5 = *(const f32x4*)(bp2 + k0 + 4);
    br6 = *(const f32x4*)(bp3 + k0); br7 = *(const f32x4*)(bp3 + k0 + 4);
  };
  bf16x8 bf0, bf1, bf2, bf3;
  auto cvtB = [&]() {
    bf0 = cvt8(br0, br1); bf1 = cvt8(br2, br3);
    bf2 = cvt8(br4, br5); bf3 = cvt8(br6, br7);
  };

  f32x4 acc[4][4];
  #pragma unroll
  for (int mi = 0; mi < 4; ++mi)
    #pragma unroll
    for (int ni = 0; ni < 4; ++ni) acc[mi][ni] = f32x4{0.f,0.f,0.f,0.f};

  const int achunk = (l4 ^ (l15 & 3)) * 16;
  auto compute = [&](int b) {
    const char* ab = smem + b * G2_BUF;
    bf16x8 af[4];
    #pragma unroll
    for (int mi = 0; mi < 4; ++mi) {
      int R = wm * 64 + mi * 16 + l15;
      af[mi] = *(const bf16x8*)(ab + R * 64 + achunk);
    }
    #pragma unroll
    for (int mi = 0; mi < 4; ++mi) {
      acc[mi][0] = __builtin_amdgcn_mfma_f32_16x16x32_bf16(af[mi], bf0, acc[mi][0], 0, 0, 0);
      acc[mi][1] = __builtin_amdgcn_mfma_f32_16x16x32_bf16(af[mi], bf1, acc[mi][1], 0, 0, 0);
      acc[mi][2] = __builtin_amdgcn_mfma_f32_16x16x32_bf16(af[mi], bf2, acc[mi][2], 0, 0, 0);
      acc[mi][3] = __builtin_amdgcn_mfma_f32_16x16x32_bf16(af[mi], bf3, acc[mi][3], 0, 0, 0);
    }
  };

  constexpr int NK = I_ / 32;   // 176
  loadB(0); stageA(0, 0);
  cvtB();
  __syncthreads();
  int cur = 0;
  for (int t = 0; t < NK; ++t) {
    if (t + 1 < NK) { loadB((t + 1) * 32); stageA(cur ^ 1, t + 1); }
    compute(cur);
    if (t + 1 < NK) cvtB();
    __syncthreads();
    cur ^= 1;
  }

  #pragma unroll
  for (int mi = 0; mi < 4; ++mi)
    #pragma unroll
    for (int ni = 0; ni < 4; ++ni)
      #pragma unroll
      for (int j = 0; j < 4; ++j) {
        int rel = wm*64 + mi*16 + l4*4 + j;
        if (m0 + rel < cnt) {
          int col = n0 + wn*64 + ni*16 + l15;
          dpart[(size_t)(off + m0 + rel) * H_ + col] = acc[mi][ni][j];
        }
      }
}

// ================= combine: out[t] = w0*d[s0] + w1*d[s1] =================
__global__ __launch_bounds__(256)
void combine_kernel(const float* __restrict__ dpart, const int* __restrict__ sot,
                    const float* __restrict__ tkw, float* __restrict__ out)
{
  int idx = blockIdx.x * 256 + threadIdx.x;     // T*H/4 total
  int t = idx >> 9;                              // H/4 = 512
  int c = (idx & 511) * 4;
  float wA = tkw[2*t], wB = tkw[2*t+1];
  int sA = sot[2*t], sB = sot[2*t+1];
  float4 a = *(const float4*)(dpart + (size_t)sA * H_ + c);
  float4 b = *(const float4*)(dpart + (size_t)sB * H_ + c);
  float4 o;
  o.x = wA*a.x + wB*b.x; o.y = wA*a.y + wB*b.y;
  o.z = wA*a.z + wB*b.z; o.w = wA*a.w + wB*b.w;
  *(float4*)(out + (size_t)t * H_ + c) = o;
}

extern "C" void kernel_launch(void* const* d_in, const int* in_sizes, int n_in,
                              void* d_out, int out_size, void* d_ws, size_t ws_size,
                              hipStream_t stream) {
  const float* hs = (const float*)d_in[0];
  const float* gw = (const float*)d_in[1];
  const float* w1 = (const float*)d_in[2];
  const float* w2 = (const float*)d_in[3];
  float* out = (float*)d_out;
  char* ws = (char*)d_ws;

  bf16_t* hb    = (bf16_t*)(ws + OFF_HB);
  bf16_t* hout  = (bf16_t*)(ws + OFF_HOUT);
  float*  dpart = (float*) (ws + OFF_DPART);
  int*    tos   = (int*)   (ws + OFF_TOS);
  int*    sot   = (int*)   (ws + OFF_SOT);
  int*    tki   = (int*)   (ws + OFF_TKI);
  float*  tkw   = (float*) (ws + OFF_TKW);
  int*    cnt   = (int*)   (ws + OFF_CNT);
  int*    offp  = (int*)   (ws + OFF_OFFS);
  int*    curp  = (int*)   (ws + OFF_CUR);

  hipMemsetAsync(ws + OFF_CNT, 0, 64, stream);   // zero expert counts each call

  router_kernel<<<T_, 256, 0, stream>>>(hs, gw, tki, tkw, cnt, hb);
  scan_kernel<<<1, 256, 0, stream>>>(cnt, tki, offp, curp, tos, sot);
  gemm1_kernel<<<16 * (2 * I_ / 128) * E_ / 8 * 8, 256, 0, stream>>>(hb, w1, tos, offp, cnt, hout);  // 16mt x 88nt x 8e
  gemm2_kernel<<<16 * (H_ / 128) * E_, 256, 0, stream>>>(hout, w2, offp, cnt, dpart);                // 16mt x 16nt x 8e
  combine_kernel<<<(T_ * H_ / 4) / 256, 256, 0, stream>>>(dpart, sot, tkw, out);
}

// Round 10
// 1023.312 us; speedup vs baseline: 2.1542x; 2.1542x over previous
//
#include <hip/hip_runtime.h>
#include <hip/hip_bf16.h>

typedef __bf16 bf16_t;
typedef __bf16 bf16x8 __attribute__((ext_vector_type(8)));
typedef float  f32x4  __attribute__((ext_vector_type(4)));

constexpr int T_ = 2048, H_ = 2048, I_ = 5632, E_ = 8, S_ = T_ * 2;

// ---- workspace layout (bytes) ----
constexpr size_t OFF_HB    = 0;                                   // bf16 hidden  [T][H]
constexpr size_t OFF_HOUT  = OFF_HB    + (size_t)T_ * H_ * 2;     // bf16 h       [S][I]
constexpr size_t OFF_DPART = OFF_HOUT  + (size_t)S_ * I_ * 2;     // f32 downpart [S][H]
constexpr size_t OFF_TOS   = OFF_DPART + (size_t)S_ * H_ * 4;     // int token_of_slot[S]
constexpr size_t OFF_SOT   = OFF_TOS   + (size_t)S_ * 4;          // int slot_of_tk[T*2]
constexpr size_t OFF_TKI   = OFF_SOT   + (size_t)S_ * 4;          // int topk_idx[T*2]
constexpr size_t OFF_TKW   = OFF_TKI   + (size_t)S_ * 4;          // f32 topk_w[T*2]
constexpr size_t OFF_CNT   = OFF_TKW   + (size_t)S_ * 4;          // int counts[E]
constexpr size_t OFF_OFFS  = OFF_CNT   + 64;                      // int offs[E]
constexpr size_t OFF_CUR   = OFF_OFFS  + 64;                      // int cursor[E]

// async global->LDS, 16B per lane. LDS dest = wave-uniform base + lane*16 (HW).
__device__ __forceinline__ void gload16(const void* g, void* l) {
  __builtin_amdgcn_global_load_lds(
      (const __attribute__((address_space(1))) void*)g,
      (__attribute__((address_space(3))) void*)l, 16, 0, 0);
}

__device__ __forceinline__ bf16x8 cvt8(f32x4 a, f32x4 b) {
  bf16x8 r;
  r[0]=(bf16_t)a[0]; r[1]=(bf16_t)a[1]; r[2]=(bf16_t)a[2]; r[3]=(bf16_t)a[3];
  r[4]=(bf16_t)b[0]; r[5]=(bf16_t)b[1]; r[6]=(bf16_t)b[2]; r[7]=(bf16_t)b[3];
  return r;
}

// ================= router: logits, softmax, top-2, bf16 convert =================
__global__ __launch_bounds__(256)
void router_kernel(const float* __restrict__ hs, const float* __restrict__ gw,
                   int* __restrict__ tki, float* __restrict__ tkw,
                   int* __restrict__ counts, bf16_t* __restrict__ hb)
{
  const int t = blockIdx.x;
  const int tid = threadIdx.x;
  const int lane = tid & 63, wid = tid >> 6;
  const float* hrow = hs + (size_t)t * H_;
  const int c0 = tid * 8;
  float4 h0 = *(const float4*)(hrow + c0);
  float4 h1 = *(const float4*)(hrow + c0 + 4);
  bf16x8 hv;
  hv[0]=(bf16_t)h0.x; hv[1]=(bf16_t)h0.y; hv[2]=(bf16_t)h0.z; hv[3]=(bf16_t)h0.w;
  hv[4]=(bf16_t)h1.x; hv[5]=(bf16_t)h1.y; hv[6]=(bf16_t)h1.z; hv[7]=(bf16_t)h1.w;
  *(bf16x8*)(hb + (size_t)t * H_ + c0) = hv;

  float acc[E_];
  #pragma unroll
  for (int e = 0; e < E_; ++e) {
    const float* g = gw + (size_t)e * H_ + c0;
    float4 g0 = *(const float4*)(g);
    float4 g1 = *(const float4*)(g + 4);
    acc[e] = h0.x*g0.x + h0.y*g0.y + h0.z*g0.z + h0.w*g0.w
           + h1.x*g1.x + h1.y*g1.y + h1.z*g1.z + h1.w*g1.w;
  }
  #pragma unroll
  for (int e = 0; e < E_; ++e)
    #pragma unroll
    for (int o = 32; o > 0; o >>= 1)
      acc[e] += __shfl_down(acc[e], o);
  __shared__ float red[4][E_];
  if (lane == 0)
    #pragma unroll
    for (int e = 0; e < E_; ++e) red[wid][e] = acc[e];
  __syncthreads();
  if (tid == 0) {
    float l[E_];
    #pragma unroll
    for (int e = 0; e < E_; ++e) l[e] = red[0][e] + red[1][e] + red[2][e] + red[3][e];
    float m = l[0];
    #pragma unroll
    for (int e = 1; e < E_; ++e) m = fmaxf(m, l[e]);
    float p[E_]; float s = 0.f;
    #pragma unroll
    for (int e = 0; e < E_; ++e) { p[e] = __expf(l[e] - m); s += p[e]; }
    int i1 = 0;
    #pragma unroll
    for (int e = 1; e < E_; ++e) if (l[e] > l[i1]) i1 = e;
    int i2 = (i1 == 0) ? 1 : 0;
    #pragma unroll
    for (int e = 0; e < E_; ++e) if (e != i1 && l[e] > l[i2]) i2 = e;
    tki[2*t] = i1; tki[2*t+1] = i2;
    tkw[2*t] = p[i1] / s; tkw[2*t+1] = p[i2] / s;
    atomicAdd(&counts[i1], 1);
    atomicAdd(&counts[i2], 1);
  }
}

// ================= scan: expert offsets + slot lists =================
__global__ void scan_kernel(const int* __restrict__ counts, const int* __restrict__ tki,
                            int* __restrict__ offs, int* __restrict__ cursor,
                            int* __restrict__ tos, int* __restrict__ sot)
{
  if (threadIdx.x == 0) {
    int run = 0;
    for (int e = 0; e < E_; ++e) { offs[e] = run; cursor[e] = run; run += counts[e]; }
  }
  __syncthreads();
  for (int t = threadIdx.x; t < T_; t += blockDim.x) {
    #pragma unroll
    for (int k = 0; k < 2; ++k) {
      int e = tki[2*t + k];
      int s = atomicAdd(&cursor[e], 1);
      tos[s] = t;
      sot[2*t + k] = s;
    }
  }
}

// ================= GEMM1: gathered hidden x w1^T, dual (gate,up), fused silu*mul =================
// BM=256, 512 threads (8 waves, 4M x 2N), BK=32. 2-phase single-barrier loop.
// A: global_load_lds (pre-swizzled source). B: one 16B bf16 LDS entry PER THREAD
// (f32x8 load -> cvt8 -> contiguous ds_write_b128), staged once per element per m-tile
// (only 2 m-tiles/expert -> half of r7's weight redundancy; B bf16 halves LDS reads, no inner cvt).
// LDS layout (A and B): pair-packed 128B rows, 8x16B slots, phys = wanted ^ (pair&7).
constexpr int G1_BUF = 16384 + 8192;   // A 16KB + B 8KB = 24KB; dbuf 48KB -> 2 blocks/CU

__global__ __launch_bounds__(512, 4)
void gemm1_kernel(const bf16_t* __restrict__ hb, const float* __restrict__ w1,
                  const int* __restrict__ tos, const int* __restrict__ offs,
                  const int* __restrict__ counts, bf16_t* __restrict__ hout)
{
  // XCD-pinned raster: expert e on XCD (bid&7); m innermost -> mt 0/1 share B strip in L2.
  const int bid = blockIdx.x;
  const int e   = bid & 7;
  const int idx = bid >> 3;          // 4 mt x 88 nt (mt 2-3 normally dead)
  const int mt  = idx & 3;
  const int nt  = idx >> 2;

  const int cnt = counts[e];
  const int m0 = mt * 256;
  if (m0 >= cnt) return;
  const int off = offs[e];
  const int n0 = nt * 64;

  const float* Wg = w1 + (size_t)e * (2 * (size_t)I_ * H_) + (size_t)n0 * H_;

  __shared__ char smem[2 * G1_BUF];

  const int tid = threadIdx.x;
  const int lane = tid & 63, wid = tid >> 6;   // 8 waves
  const int wm = wid >> 1, wn = wid & 1;       // 4M x 2N
  const int l15 = lane & 15, l4 = lane >> 4;

  // --- A staging: 16 chunks of 1KB (8 pairs x 128B); wave stages q = wid*2+{0,1}.
  const bf16_t* agp[2]; int aoff[2];
  #pragma unroll
  for (int i = 0; i < 2; ++i) {
    int q = wid * 2 + i;
    int w = (lane & 7) ^ ((lane >> 3) & 7);          // wanted slot (pair&7 == lane>>3)
    int row = 2 * (q * 8 + (lane >> 3)) + (w >> 2);  // token row 0..255
    int slot = off + m0 + row, mx = off + cnt - 1;
    if (slot > mx) slot = mx;                        // clamp pad rows (masked at store)
    agp[i]  = hb + (size_t)tos[slot] * H_ + (w & 3) * 8;
    aoff[i] = q * 1024;
  }
  auto stageA = [&](int b, int t) {
    char* ab = smem + b * G1_BUF;
    #pragma unroll
    for (int i = 0; i < 2; ++i) gload16(agp[i] + t * 32, ab + aoff[i]);
  };

  // --- B staging: 512 entries (128 n-rows x 4 k-slots as 64 pairs x 8 slots), 1/thread.
  // entry = tid: p = tid>>3, phys = tid&7, wanted = phys^(p&7); n = 2p+(w>>2) (0-63 gate, 64-127 up).
  const int bp = tid >> 3, bw = (tid & 7) ^ (bp & 7);
  const int bn = 2 * bp + (bw >> 2);
  const size_t brow = (bn < 64) ? (size_t)bn : (size_t)(I_ + bn - 64);
  const float* bsrc = Wg + brow * H_ + (bw & 3) * 8;
  f32x4 bx, by;
  auto loadB  = [&](int k0) { bx = *(const f32x4*)(bsrc + k0); by = *(const f32x4*)(bsrc + k0 + 4); };
  auto writeB = [&](int b)  { *(bf16x8*)(smem + b * G1_BUF + 16384 + tid * 16) = cvt8(bx, by); };

  f32x4 accg[4][2], accu[4][2];
  #pragma unroll
  for (int mi = 0; mi < 4; ++mi)
    #pragma unroll
    for (int ni = 0; ni < 2; ++ni) {
      accg[mi][ni] = f32x4{0.f,0.f,0.f,0.f};
      accu[mi][ni] = f32x4{0.f,0.f,0.f,0.f};
    }

  // read-side lane constants (pair-packed XOR layout; (l15>>1)&7 is pair&7 since bases are x8)
  const int phys = ((((l15 & 1) << 2) | l4) ^ ((l15 >> 1) & 7)) * 16;

  auto compute = [&](int b) {
    const char* ab = smem + b * G1_BUF;
    const char* bb = ab + 16384;
    bf16x8 af[4], bgf[2], buf2[2];
    #pragma unroll
    for (int mi = 0; mi < 4; ++mi) {
      int pr = wm * 32 + mi * 8 + (l15 >> 1);      // A pair of row wm*64+mi*16+l15
      af[mi] = *(const bf16x8*)(ab + pr * 128 + phys);
    }
    #pragma unroll
    for (int ni = 0; ni < 2; ++ni) {
      int pb = wn * 16 + ni * 8 + (l15 >> 1);      // B pair (gate); up = +32 pairs
      bgf[ni]  = *(const bf16x8*)(bb + pb * 128 + phys);
      buf2[ni] = *(const bf16x8*)(bb + (pb + 32) * 128 + phys);
    }
    #pragma unroll
    for (int mi = 0; mi < 4; ++mi)
      #pragma unroll
      for (int ni = 0; ni < 2; ++ni) {
        accg[mi][ni] = __builtin_amdgcn_mfma_f32_16x16x32_bf16(af[mi], bgf[ni],  accg[mi][ni], 0, 0, 0);
        accu[mi][ni] = __builtin_amdgcn_mfma_f32_16x16x32_bf16(af[mi], buf2[ni], accu[mi][ni], 0, 0, 0);
      }
  };

  constexpr int NK = H_ / 32;   // 64
  stageA(0, 0); loadB(0); writeB(0);
  __syncthreads();
  int cur = 0;
  for (int t = 0; t < NK; ++t) {
    if (t + 1 < NK) { stageA(cur ^ 1, t + 1); loadB((t + 1) * 32); }
    compute(cur);
    if (t + 1 < NK) writeB(cur ^ 1);
    __syncthreads();
    cur ^= 1;
  }

  // epilogue: silu(g)*u -> bf16 h[slot][i]   (C/D map: row=(lane>>4)*4+j, col=lane&15)
  #pragma unroll
  for (int mi = 0; mi < 4; ++mi)
    #pragma unroll
    for (int ni = 0; ni < 2; ++ni)
      #pragma unroll
      for (int j = 0; j < 4; ++j) {
        int rel = wm*64 + mi*16 + l4*4 + j;
        if (m0 + rel < cnt) {
          int col = n0 + wn*32 + ni*16 + l15;
          float g = accg[mi][ni][j];
          float u = accu[mi][ni][j];
          float hvv = (g / (1.0f + __expf(-g))) * u;
          hout[(size_t)(off + m0 + rel) * I_ + col] = (bf16_t)hvv;
        }
      }
}

// ================= GEMM2: h x w2^T -> per-slot partial (f32) =================
// Same structure: BM=256, BN=64, 512 threads, B bf16 4KB (256 entries, threads<256 stage).
constexpr int G2_BUF = 16384 + 4096;   // 20KB; dbuf 40KB

__global__ __launch_bounds__(512, 4)
void gemm2_kernel(const bf16_t* __restrict__ hbuf, const float* __restrict__ w2,
                  const int* __restrict__ offs, const int* __restrict__ counts,
                  float* __restrict__ dpart)
{
  const int bid = blockIdx.x;
  const int e   = bid & 7;
  const int idx = bid >> 3;          // 4 mt x 32 nt
  const int mt  = idx & 3;
  const int nt  = idx >> 2;

  const int cnt = counts[e];
  const int m0 = mt * 256;
  if (m0 >= cnt) return;
  const int off = offs[e];
  const int n0 = nt * 64;
  const float* W = w2 + (size_t)e * ((size_t)H_ * I_) + (size_t)n0 * I_;

  __shared__ char smem[2 * G2_BUF];

  const int tid = threadIdx.x;
  const int lane = tid & 63, wid = tid >> 6;
  const int wm = wid >> 1, wn = wid & 1;
  const int l15 = lane & 15, l4 = lane >> 4;

  const bf16_t* agp[2]; int aoff[2];
  #pragma unroll
  for (int i = 0; i < 2; ++i) {
    int q = wid * 2 + i;
    int w = (lane & 7) ^ ((lane >> 3) & 7);
    int row = 2 * (q * 8 + (lane >> 3)) + (w >> 2);
    int slot = off + m0 + row, mx = off + cnt - 1;
    if (slot > mx) slot = mx;
    agp[i]  = hbuf + (size_t)slot * I_ + (w & 3) * 8;
    aoff[i] = q * 1024;
  }
  auto stageA = [&](int b, int t) {
    char* ab = smem + b * G2_BUF;
    #pragma unroll
    for (int i = 0; i < 2; ++i) gload16(agp[i] + t * 32, ab + aoff[i]);
  };

  // B: 256 entries (64 rows x 4 slots = 32 pairs x 8); threads < 256 stage one each.
  const int bp = tid >> 3, bw = (tid & 7) ^ (bp & 7);
  const int bn = 2 * bp + (bw >> 2);                 // 0..63 (valid when tid<256)
  const float* bsrc = W + (size_t)bn * I_ + (bw & 3) * 8;
  f32x4 bx, by;
  auto loadB  = [&](int k0) { if (tid < 256) { bx = *(const f32x4*)(bsrc + k0); by = *(const f32x4*)(bsrc + k0 + 4); } };
  auto writeB = [&](int b)  { if (tid < 256) *(bf16x8*)(smem + b * G2_BUF + 16384 + tid * 16) = cvt8(bx, by); };

  f32x4 acc[4][2];
  #pragma unroll
  for (int mi = 0; mi < 4; ++mi)
    #pragma unroll
    for (int ni = 0; ni < 2; ++ni) acc[mi][ni] = f32x4{0.f,0.f,0.f,0.f};

  const int phys = ((((l15 & 1) << 2) | l4) ^ ((l15 >> 1) & 7)) * 16;

  auto compute = [&](int b) {
    const char* ab = smem + b * G2_BUF;
    const char* bb = ab + 16384;
    bf16x8 af[4], bf[2];
    #pragma unroll
    for (int mi = 0; mi < 4; ++mi) {
      int pr = wm * 32 + mi * 8 + (l15 >> 1);
      af[mi] = *(const bf16x8*)(ab + pr * 128 + phys);
    }
    #pragma unroll
    for (int ni = 0; ni < 2; ++ni) {
      int pb = wn * 16 + ni * 8 + (l15 >> 1);
      bf[ni] = *(const bf16x8*)(bb + pb * 128 + phys);
    }
    #pragma unroll
    for (int mi = 0; mi < 4; ++mi)
      #pragma unroll
      for (int ni = 0; ni < 2; ++ni)
        acc[mi][ni] = __builtin_amdgcn_mfma_f32_16x16x32_bf16(af[mi], bf[ni], acc[mi][ni], 0, 0, 0);
  };

  constexpr int NK = I_ / 32;   // 176
  stageA(0, 0); loadB(0); writeB(0);
  __syncthreads();
  int cur = 0;
  for (int t = 0; t < NK; ++t) {
    if (t + 1 < NK) { stageA(cur ^ 1, t + 1); loadB((t + 1) * 32); }
    compute(cur);
    if (t + 1 < NK) writeB(cur ^ 1);
    __syncthreads();
    cur ^= 1;
  }

  #pragma unroll
  for (int mi = 0; mi < 4; ++mi)
    #pragma unroll
    for (int ni = 0; ni < 2; ++ni)
      #pragma unroll
      for (int j = 0; j < 4; ++j) {
        int rel = wm*64 + mi*16 + l4*4 + j;
        if (m0 + rel < cnt) {
          int col = n0 + wn*32 + ni*16 + l15;
          dpart[(size_t)(off + m0 + rel) * H_ + col] = acc[mi][ni][j];
        }
      }
}

// ================= combine: out[t] = w0*d[s0] + w1*d[s1] =================
__global__ __launch_bounds__(256)
void combine_kernel(const float* __restrict__ dpart, const int* __restrict__ sot,
                    const float* __restrict__ tkw, float* __restrict__ out)
{
  int idx = blockIdx.x * 256 + threadIdx.x;     // T*H/4 total
  int t = idx >> 9;                              // H/4 = 512
  int c = (idx & 511) * 4;
  float wA = tkw[2*t], wB = tkw[2*t+1];
  int sA = sot[2*t], sB = sot[2*t+1];
  float4 a = *(const float4*)(dpart + (size_t)sA * H_ + c);
  float4 b = *(const float4*)(dpart + (size_t)sB * H_ + c);
  float4 o;
  o.x = wA*a.x + wB*b.x; o.y = wA*a.y + wB*b.y;
  o.z = wA*a.z + wB*b.z; o.w = wA*a.w + wB*b.w;
  *(float4*)(out + (size_t)t * H_ + c) = o;
}

extern "C" void kernel_launch(void* const* d_in, const int* in_sizes, int n_in,
                              void* d_out, int out_size, void* d_ws, size_t ws_size,
                              hipStream_t stream) {
  const float* hs = (const float*)d_in[0];
  const float* gw = (const float*)d_in[1];
  const float* w1 = (const float*)d_in[2];
  const float* w2 = (const float*)d_in[3];
  float* out = (float*)d_out;
  char* ws = (char*)d_ws;

  bf16_t* hb    = (bf16_t*)(ws + OFF_HB);
  bf16_t* hout  = (bf16_t*)(ws + OFF_HOUT);
  float*  dpart = (float*) (ws + OFF_DPART);
  int*    tos   = (int*)   (ws + OFF_TOS);
  int*    sot   = (int*)   (ws + OFF_SOT);
  int*    tki   = (int*)   (ws + OFF_TKI);
  float*  tkw   = (float*) (ws + OFF_TKW);
  int*    cnt   = (int*)   (ws + OFF_CNT);
  int*    offp  = (int*)   (ws + OFF_OFFS);
  int*    curp  = (int*)   (ws + OFF_CUR);

  hipMemsetAsync(ws + OFF_CNT, 0, 64, stream);   // zero expert counts each call

  router_kernel<<<T_, 256, 0, stream>>>(hs, gw, tki, tkw, cnt, hb);
  scan_kernel<<<1, 256, 0, stream>>>(cnt, tki, offp, curp, tos, sot);
  gemm1_kernel<<<4 * (2 * I_ / 128) * E_, 512, 0, stream>>>(hb, w1, tos, offp, cnt, hout);  // 4mt x 88nt x 8e
  gemm2_kernel<<<4 * (H_ / 64) * E_, 512, 0, stream>>>(hout, w2, offp, cnt, dpart);         // 4mt x 32nt x 8e
  combine_kernel<<<(T_ * H_ / 4) / 256, 256, 0, stream>>>(dpart, sot, tkw, out);
}